// Round 4
// baseline (12164.542 us; speedup 1.0000x reference)
//
#include <hip/hip_runtime.h>
#include <cstdint>
#include <cstddef>

typedef _Float16 h2_t __attribute__((ext_vector_type(2)));
typedef unsigned int uint;

#define BB 128
#define TT 512
#define GLEAD 16

// ---- ws layout (bytes) ----
#define OFF_PHH0 0u          // 48*512*16 = 393216
#define OFF_PHH1 393216u     // 393216
#define OFF_PB1  786432u     // 1024*24*16 = 393216
#define OFF_PB0  1179648u    // 1024*6*16  = 98304
#define OFF_SYNC 1277952u    // pL0 @0 (64*64B), pL1 @4096, pB @8192 (128*64B) = 16384
#define OFF_H2O  1294336u    // 128*256*4 = 131072
#define OFF_H1R  1425408u    // 32*128*128*4 = 2097152
#define OFF_G0R  3522560u    // 32*256*128*16 = 16777216
#define OFF_G1R  20299776u   // 16777216  (end 37076992 ~ 37 MB)

__device__ __forceinline__ uint pack2(float a, float b){
  h2_t h; h.x = (_Float16)a; h.y = (_Float16)b;
  return __builtin_bit_cast(uint, h);
}
__device__ __forceinline__ float dot2(uint w, uint h, float acc){
  return __builtin_amdgcn_fdot2(__builtin_bit_cast(h2_t, w),
                                __builtin_bit_cast(h2_t, h), acc, false);
}
__device__ __forceinline__ float d16(uint4 w, uint4 h, float a){
  a = dot2(w.x,h.x,a); a = dot2(w.y,h.y,a);
  a = dot2(w.z,h.z,a); a = dot2(w.w,h.w,a);
  return a;
}
template<int CTRL>
__device__ __forceinline__ float dpp_addf(float x){
  int p = __builtin_amdgcn_update_dpp(0, __float_as_int(x), CTRL, 0xF, 0xF, true);
  return x + __int_as_float(p);
}
template<int CTRL>
__device__ __forceinline__ float dpp_movf(float x){
  return __int_as_float(__builtin_amdgcn_update_dpp(0, __float_as_int(x), CTRL, 0xF, 0xF, true));
}
template<int CTRL>
__device__ __forceinline__ uint dpp_movu(uint x){
  return (uint)__builtin_amdgcn_update_dpp(0, (int)x, CTRL, 0xF, 0xF, true);
}
template<int CTRL>
__device__ __forceinline__ int dpp_mini(int x){
  int p = __builtin_amdgcn_update_dpp(0, x, CTRL, 0xF, 0xF, true);
  return min(x, p);
}
// sum over 4-lane quads (kq = lane&3), result in all 4 lanes
__device__ __forceinline__ float red4(float x){
  x = dpp_addf<0xB1>(x); x = dpp_addf<0x4E>(x);
  return x;
}
// sum over 8-lane groups (q = lane&7), result in all 8 lanes (verified r1/r2)
__device__ __forceinline__ float red8(float x){
  x = dpp_addf<0xB1>(x); x = dpp_addf<0x4E>(x);
  int y = __builtin_amdgcn_ds_swizzle(__float_as_int(x), 0x101F);
  return x + __int_as_float(y);
}
// min over 16-lane rows (row_ror, verified add-version r3)
__device__ __forceinline__ int minred16(int x){
  x = dpp_mini<0x128>(x); x = dpp_mini<0x124>(x);
  x = dpp_mini<0x122>(x); x = dpp_mini<0x121>(x);
  return x;
}
// min over 8-lane groups
__device__ __forceinline__ int minred8(int x){
  x = dpp_mini<0xB1>(x); x = dpp_mini<0x4E>(x);
  int y = __builtin_amdgcn_ds_swizzle(x, 0x101F);
  return min(x, y);
}
__device__ __forceinline__ float sigf(float x){ return 1.0f/(1.0f+__expf(-x)); }
__device__ __forceinline__ float tanhf_(float x){
  x = fminf(15.0f, fmaxf(-15.0f, x));
  float e = __expf(2.0f*x);
  return (e-1.0f)/(e+1.0f);
}
__device__ __forceinline__ float pick4(float a0,float a1,float a2,float a3,int s){
  float x = (s&1)? a1:a0, y = (s&1)? a3:a2;
  return (s&2)? y:x;
}

// =================== prep: pack fp32 weights -> f16 images ===================
// PHH (l0/l1 recurrence, 512 thr, 8-way k): [c(48)][tid(512)] uint4;
//   q=tid&7,u=tid>>3, g=c>>4,s=(c>>2)&3,k4=c&3: row=g*256+4u+s, col=32q+8k4+2e.
// PB1 (B gx1 wts): [slot(1024)][c(24)] uint4; slot=((n*4+kq)*16+r_l);
//   i=c>>3,k4=c&7: row=48n+3r_l+i, col=64kq+8k4+2e.
// PB0: [slot][c(6)] uint4; i=c>>1,k4=c&1: row same, col=16kq+8k4+2e.
__global__ void prep_kernel(const float* __restrict__ W_ih0, const float* __restrict__ W_hh0,
                            const float* __restrict__ W_ih1, const float* __restrict__ W_hh1,
                            uint* __restrict__ PHH0, uint* __restrict__ PHH1,
                            uint* __restrict__ PB1, uint* __restrict__ PB0)
{
  int i = blockIdx.x*256 + threadIdx.x;
  if (i < 196608) {
    const float* W = (i < 98304) ? W_hh0 : W_hh1;
    uint* dst = (i < 98304) ? PHH0 : PHH1;
    int j = i % 98304;
    int e = j&3, r2 = j>>2;
    int tid = r2 & 511, c = r2 >> 9;
    int q = tid&7, u = tid>>3, g = c>>4, s = (c>>2)&3, k4 = c&3;
    int row = g*256 + 4*u + s, col = 32*q + 8*k4 + 2*e;
    dst[j] = pack2(W[row*256+col], W[row*256+col+1]);
  } else if (i < 294912) {
    int j = i - 196608;
    int e = j&3, r2 = j>>2;
    int c = r2 % 24, slot = r2 / 24;
    int r_l = slot & 15, kq = (slot>>4)&3, n = slot>>6;
    int i3 = c>>3, k4 = c&7;
    int row = 48*n + 3*r_l + i3, col = 64*kq + 8*k4 + 2*e;
    PB1[j] = pack2(W_ih1[row*256+col], W_ih1[row*256+col+1]);
  } else if (i < 319488) {
    int j = i - 294912;
    int e = j&3, r2 = j>>2;
    int c = r2 % 6, slot = r2 / 6;
    int r_l = slot & 15, kq = (slot>>4)&3, n = slot>>6;
    int i3 = c>>1, k4 = c&1;
    int row = 48*n + 3*r_l + i3, col = 16*kq + 8*k4 + 2*e;
    PB0[j] = pack2(W_ih0[row*64+col], W_ih0[row*64+col+1]);
  }
}

// =================== recurrence role (l0 / l1) ===================
// 512 thr, 2 batches/block. q=tid&7 (32-col k-slice), u=tid>>3 (units 4u..4u+3),
// sl=q&3, bb=q>>2: gate lane handles (batch bb, unit j=4u+sl).
// W_hh gates r,z in RF (whh[32]); gate n in LDS (wn, 128 KB).
// h (f16) in LDS, double-buffered, padded slices (20 uints per 16) -> conflict-free.
// gx (input preactivations incl. b_ih) read from ring, prefetched one step ahead.
template<bool IS_L0>
__device__ __forceinline__ void rec_role(
    const uint4* __restrict__ PHH, const float4* __restrict__ GXR,
    const float* __restrict__ bhh,
    uint* __restrict__ h1r, float* __restrict__ h2o,
    int* __restrict__ pSelf, int* __restrict__ pB,
    int local, uint* lds_u, int tid)
{
  const int q = tid & 7, u = tid >> 3, sl = q & 3, bb = q >> 2;
  const int lane = tid & 63;
  const int m = local >> 3;
  uint4* wn4 = (uint4*)lds_u;                 // [16][512] uint4
  uint*  hs  = lds_u + 32768;                 // 2 buf * (2 bb * 160 uints)

  uint4 whh[32];
  #pragma unroll
  for (int c = 0; c < 32; ++c) whh[c] = PHH[c*512 + tid];
  #pragma unroll
  for (int cc = 0; cc < 16; ++cc) wn4[cc*512 + tid] = PHH[(32+cc)*512 + tid];
  for (int k = tid; k < 640; k += 512) hs[k] = 0;

  const int j = 4*u + sl;
  const float bhr = bhh[j], bhz = bhh[256+j], bhn = bhh[512+j];
  const int batch = 2*local + bb;
  const int pidx = (m + 8*(lane & 15)) * 16;  // 16 B-blocks of group m
  float h_old = 0.f;
  float4 gxv = make_float4(0.f,0.f,0.f,0.f);
  bool have = false;
  __syncthreads();
  int cur = 0;
  #pragma unroll 1
  for (int t = 0; t < TT; ++t) {
    const int slot = t & 31;
    if (!have) {
      const int need = IS_L0 ? max(1, t - (GLEAD-2)) : (t + 2);
      int pv;
      do {
        pv = minred16(__hip_atomic_load(pB + pidx, __ATOMIC_RELAXED, __HIP_MEMORY_SCOPE_AGENT));
        pv = __builtin_amdgcn_readfirstlane(pv);
        if (pv < need) __builtin_amdgcn_s_sleep(4);
      } while (pv < need);
      __builtin_amdgcn_fence(__ATOMIC_ACQUIRE, "agent");
      gxv = GXR[(slot*256 + j)*128 + batch];
    }
    int pv2 = __hip_atomic_load(pB + pidx, __ATOMIC_RELAXED, __HIP_MEMORY_SCOPE_AGENT);

    float aR[2][4] = {{0,0,0,0},{0,0,0,0}};
    float aZ[2][4] = {{0,0,0,0},{0,0,0,0}};
    float aN[2][4] = {{0,0,0,0},{0,0,0,0}};
    const uint4* hc = (const uint4*)(hs + cur*320);
    #pragma unroll
    for (int k4 = 0; k4 < 4; ++k4) {
      uint4 h0  = hc[5*q + k4];
      uint4 h1v = hc[40 + 5*q + k4];
      #pragma unroll
      for (int s = 0; s < 4; ++s) {
        uint4 wr = whh[(0*4+s)*4 + k4];
        aR[0][s] = d16(wr, h0, aR[0][s]);
        aR[1][s] = d16(wr, h1v, aR[1][s]);
        uint4 wz = whh[(1*4+s)*4 + k4];
        aZ[0][s] = d16(wz, h0, aZ[0][s]);
        aZ[1][s] = d16(wz, h1v, aZ[1][s]);
        uint4 wnv = wn4[(4*s + k4)*512 + tid];
        aN[0][s] = d16(wnv, h0, aN[0][s]);
        aN[1][s] = d16(wnv, h1v, aN[1][s]);
      }
    }
    #pragma unroll
    for (int s = 0; s < 4; ++s) {
      aR[0][s]=red8(aR[0][s]); aR[1][s]=red8(aR[1][s]);
      aZ[0][s]=red8(aZ[0][s]); aZ[1][s]=red8(aZ[1][s]);
      aN[0][s]=red8(aN[0][s]); aN[1][s]=red8(aN[1][s]);
    }
    float R = bb ? pick4(aR[1][0],aR[1][1],aR[1][2],aR[1][3],sl)
                 : pick4(aR[0][0],aR[0][1],aR[0][2],aR[0][3],sl);
    float Z = bb ? pick4(aZ[1][0],aZ[1][1],aZ[1][2],aZ[1][3],sl)
                 : pick4(aZ[0][0],aZ[0][1],aZ[0][2],aZ[0][3],sl);
    float N = bb ? pick4(aN[1][0],aN[1][1],aN[1][2],aN[1][3],sl)
                 : pick4(aN[0][0],aN[0][1],aN[0][2],aN[0][3],sl);
    float r = sigf(gxv.x + R + bhr);
    float z = sigf(gxv.y + Z + bhz);
    float n = tanhf_(gxv.z + r*(N + bhn));
    float hn = z*(h_old - n) + n;
    h_old = hn;
    uint v  = pack2(hn, dpp_movf<0xB1>(hn));
    uint v2 = dpp_movu<0x4E>(v);
    if (sl == 0) {
      const int ui = 2*u;
      uint* dsh = hs + (cur^1)*320 + bb*160 + 20*(ui>>4) + (ui & 15);
      dsh[0] = v; dsh[1] = v2;
      if (IS_L0) {
        *(uint2*)(h1r + slot*16384 + batch*128 + ui) = make_uint2(v, v2);
      }
    }
    if (!IS_L0 && t == TT-1) h2o[batch*256 + j] = hn;
    // prefetch gx[t+1]
    pv2 = minred16(pv2);
    pv2 = __builtin_amdgcn_readfirstlane(pv2);
    have = false;
    if (t+1 < TT) {
      const int neednx = IS_L0 ? max(1, t+1 - (GLEAD-2)) : (t + 3);
      if (pv2 >= neednx) {
        __builtin_amdgcn_fence(__ATOMIC_ACQUIRE, "agent");
        gxv = GXR[(((t+1)&31)*256 + j)*128 + batch];
        have = true;
      }
    }
    __syncthreads();
    if (tid == 0)
      __hip_atomic_store(pSelf, t+1, __ATOMIC_RELEASE, __HIP_MEMORY_SCOPE_AGENT);
    cur ^= 1;
  }
}

// =================== B role: gx GEMM tiles ===================
// Block nb: m=nb&7 (batches 16m..+16), n=nb>>3 (rows 48n..+48 of 768).
// Iter tau: gx1[tau] from h1ring (tau>=0) and gx0[tau+GLEAD] from x.
// Weights register-resident; h/x tiles staged in LDS (padded rows).
__device__ __forceinline__ void b_role(
    const float* __restrict__ x,
    const uint4* __restrict__ PB1p, const uint4* __restrict__ PB0p,
    const float* __restrict__ b_ih0, const float* __restrict__ b_ih1,
    const uint* __restrict__ h1r, float* __restrict__ g0r, float* __restrict__ g1r,
    int* __restrict__ pL0, int* __restrict__ pL1, int* __restrict__ pSelf,
    int nb, uint* lds_u, int tid)
{
  const int m = nb & 7, n = nb >> 3;
  const int kq = tid & 3, rb = tid >> 2;
  const int r_l = rb >> 3, b_l = rb & 7;
  const int lane = tid & 63;
  uint4* hT = (uint4*)lds_u;              // [16][33] uint4 (padded)
  uint*  xT = lds_u + 2112;               // [16][36] uints (padded)
  const int wslot = (n*4 + kq)*16 + r_l;
  uint4 w1[24], w0[6];
  #pragma unroll
  for (int c = 0; c < 24; ++c) w1[c] = PB1p[wslot*24 + c];
  #pragma unroll
  for (int c = 0; c < 6; ++c)  w0[c] = PB0p[wslot*6 + c];
  int gI[3], jI[3]; float bi1[3], bi0[3];
  #pragma unroll
  for (int i = 0; i < 3; ++i) {
    int row = 48*n + 3*r_l + i;
    gI[i] = row >> 8; jI[i] = row & 255;
    bi1[i] = b_ih1[row]; bi0[i] = b_ih0[row];
  }
  const int pidx = (8*m + (lane & 7)) * 16;
  #pragma unroll 1
  for (int tau = -GLEAD; tau < TT; ++tau) {
    const int tg = tau + GLEAD;
    if (tau >= 0) {
      int pv;
      do {
        int a = __hip_atomic_load(pL0 + pidx, __ATOMIC_RELAXED, __HIP_MEMORY_SCOPE_AGENT);
        int b = __hip_atomic_load(pL1 + pidx, __ATOMIC_RELAXED, __HIP_MEMORY_SCOPE_AGENT);
        pv = minred8(min(a, b + 32));
        pv = __builtin_amdgcn_readfirstlane(pv);
        if (pv < tau+1) __builtin_amdgcn_s_sleep(8);
      } while (pv < tau+1);
      __builtin_amdgcn_fence(__ATOMIC_ACQUIRE, "agent");
      const uint4* src = (const uint4*)(h1r + (uint)(tau&31)*16384 + (uint)(16*m)*128);
      hT[(tid>>5)*33 + (tid&31)] = src[tid];
    }
    if (tg < TT && tid < 256) {
      const int bi = tid >> 4, cx = tid & 15;
      float4 xv = ((const float4*)x)[((size_t)(16*m + bi)*TT + tg)*16 + cx];
      uint* xd = xT + bi*36 + 2*cx;
      xd[0] = pack2(xv.x, xv.y);
      xd[1] = pack2(xv.z, xv.w);
    }
    __syncthreads();
    float a1[3][2] = {{0,0},{0,0},{0,0}};
    float a0[3][2] = {{0,0},{0,0},{0,0}};
    if (tau >= 0) {
      #pragma unroll
      for (int k4 = 0; k4 < 8; ++k4) {
        uint4 hA = hT[(2*b_l)*33   + 8*kq + k4];
        uint4 hB = hT[(2*b_l+1)*33 + 8*kq + k4];
        #pragma unroll
        for (int i = 0; i < 3; ++i) {
          a1[i][0] = d16(w1[i*8+k4], hA, a1[i][0]);
          a1[i][1] = d16(w1[i*8+k4], hB, a1[i][1]);
        }
      }
    }
    if (tg < TT) {
      #pragma unroll
      for (int k4 = 0; k4 < 2; ++k4) {
        uint4 xA = *(const uint4*)(xT + (2*b_l)*36   + 8*kq + 4*k4);
        uint4 xB = *(const uint4*)(xT + (2*b_l+1)*36 + 8*kq + 4*k4);
        #pragma unroll
        for (int i = 0; i < 3; ++i) {
          a0[i][0] = d16(w0[i*2+k4], xA, a0[i][0]);
          a0[i][1] = d16(w0[i*2+k4], xB, a0[i][1]);
        }
      }
    }
    #pragma unroll
    for (int i = 0; i < 3; ++i) {
      a1[i][0] = red4(a1[i][0]); a1[i][1] = red4(a1[i][1]);
      a0[i][0] = red4(a0[i][0]); a0[i][1] = red4(a0[i][1]);
    }
    if (kq == 0) {
      const int bat = 16*m + 2*b_l;
      #pragma unroll
      for (int i = 0; i < 3; ++i) {
        if (tau >= 0) {
          float* d1 = g1r + (((size_t)(tau&31)*256 + jI[i])*128 + bat)*4 + gI[i];
          d1[0] = a1[i][0] + bi1[i];
          d1[4] = a1[i][1] + bi1[i];
        }
        if (tg < TT) {
          float* d0 = g0r + (((size_t)(tg&31)*256 + jI[i])*128 + bat)*4 + gI[i];
          d0[0] = a0[i][0] + bi0[i];
          d0[4] = a0[i][1] + bi0[i];
        }
      }
    }
    __syncthreads();
    if (tid == 0 && tau >= -1)
      __hip_atomic_store(pSelf, tau + 2, __ATOMIC_RELEASE, __HIP_MEMORY_SCOPE_AGENT);
  }
}

__global__ __launch_bounds__(512) __attribute__((amdgpu_waves_per_eu(2,2)))
void gru_fused(const float* __restrict__ x,
               const float* __restrict__ b_ih0, const float* __restrict__ b_hh0,
               const float* __restrict__ b_ih1, const float* __restrict__ b_hh1,
               char* __restrict__ ws)
{
  extern __shared__ uint lds_u[];
  const int tid = threadIdx.x;
  const int blk = blockIdx.x;
  int* pL0 = (int*)(ws + OFF_SYNC);
  int* pL1 = (int*)(ws + OFF_SYNC + 4096);
  int* pB  = (int*)(ws + OFF_SYNC + 8192);
  if (blk < 64) {
    rec_role<true>((const uint4*)(ws + OFF_PHH0), (const float4*)(ws + OFF_G0R),
                   b_hh0, (uint*)(ws + OFF_H1R), nullptr,
                   pL0 + blk*16, pB, blk, lds_u, tid);
  } else if (blk < 128) {
    rec_role<false>((const uint4*)(ws + OFF_PHH1), (const float4*)(ws + OFF_G1R),
                    b_hh1, nullptr, (float*)(ws + OFF_H2O),
                    pL1 + (blk-64)*16, pB, blk-64, lds_u, tid);
  } else {
    b_role(x, (const uint4*)(ws + OFF_PB1), (const uint4*)(ws + OFF_PB0),
           b_ih0, b_ih1, (const uint*)(ws + OFF_H1R),
           (float*)(ws + OFF_G0R), (float*)(ws + OFF_G1R),
           pL0, pL1, pB + (blk-128)*16, blk-128, lds_u, tid);
  }
}

// =================== MLP head ===================
__global__ __launch_bounds__(128) void mlp_kernel(
    const float* __restrict__ h2, const float* __restrict__ W1,
    const float* __restrict__ b1, const float* __restrict__ W2,
    const float* __restrict__ b2, float* __restrict__ out)
{
  __shared__ float hls[256];
  __shared__ float red[128];
  const int b = blockIdx.x, tid = threadIdx.x;
  if (tid < 64) ((float4*)hls)[tid] = ((const float4*)(h2 + (size_t)b*256))[tid];
  __syncthreads();
  float acc = b1[tid];
  const float4* w4 = (const float4*)(W1 + (size_t)tid*256);
  const float4* h4 = (const float4*)hls;
  #pragma unroll 8
  for (int k = 0; k < 64; ++k) {
    float4 w = w4[k]; float4 h = h4[k];
    acc = fmaf(w.x,h.x,acc); acc = fmaf(w.y,h.y,acc);
    acc = fmaf(w.z,h.z,acc); acc = fmaf(w.w,h.w,acc);
  }
  red[tid] = fmaxf(acc, 0.0f) * W2[tid];
  __syncthreads();
  for (int s = 64; s > 0; s >>= 1) {
    if (tid < s) red[tid] += red[tid + s];
    __syncthreads();
  }
  if (tid == 0) out[b] = red[0] + b2[0];
}

extern "C" void kernel_launch(void* const* d_in, const int* in_sizes, int n_in,
                              void* d_out, int out_size, void* d_ws, size_t ws_size,
                              hipStream_t stream)
{
  const float* x     = (const float*)d_in[0];
  const float* W_ih0 = (const float*)d_in[1];
  const float* W_hh0 = (const float*)d_in[2];
  const float* b_ih0 = (const float*)d_in[3];
  const float* b_hh0 = (const float*)d_in[4];
  const float* W_ih1 = (const float*)d_in[5];
  const float* W_hh1 = (const float*)d_in[6];
  const float* b_ih1 = (const float*)d_in[7];
  const float* b_hh1 = (const float*)d_in[8];
  const float* W1    = (const float*)d_in[9];
  const float* b1    = (const float*)d_in[10];
  const float* W2    = (const float*)d_in[11];
  const float* b2    = (const float*)d_in[12];

  char* ws = (char*)d_ws;
  const int dyn_lds = 33408 * 4;   // 133632 B (wn 128K + hs 2.5K; B uses ~11K)
  (void)hipFuncSetAttribute(reinterpret_cast<const void*>(gru_fused),
                            hipFuncAttributeMaxDynamicSharedMemorySize, dyn_lds);

  hipMemsetAsync(ws + OFF_SYNC, 0, 16384, stream);
  prep_kernel<<<1248, 256, 0, stream>>>(W_ih0, W_hh0, W_ih1, W_hh1,
                                        (uint*)(ws + OFF_PHH0), (uint*)(ws + OFF_PHH1),
                                        (uint*)(ws + OFF_PB1),  (uint*)(ws + OFF_PB0));
  gru_fused<<<256, 512, dyn_lds, stream>>>(x, b_ih0, b_hh0, b_ih1, b_hh1, ws);
  mlp_kernel<<<BB, 128, 0, stream>>>((float*)(ws + OFF_H2O), W1, b1, W2, b2, (float*)d_out);
}

// Round 5
// 2390.168 us; speedup vs baseline: 5.0894x; 5.0894x over previous
//
#include <hip/hip_runtime.h>
#include <cstdint>
#include <cstddef>

typedef _Float16 h2_t __attribute__((ext_vector_type(2)));
typedef unsigned int uint;
typedef unsigned short ushortt;

#define BB 128
#define TT 512

// ---- ws layout (bytes) ----
#define OFF_PH0 0u            // 24*1024*16 = 393216
#define OFF_PH1 393216u       // 393216
#define OFF_PI0 786432u       // 24576*4 = 98304
#define OFF_PI1 884736u       // 98304*4 = 393216
#define OFF_H2O 1277952u      // 128*256*4 = 131072
#define OFF_H1  1409024u      // 128*512*128*4 = 33554432
#define OFF_GX  34963456u     // 128*512*768*2 = 100663296  (end ~135.6 MB)

__device__ __forceinline__ uint pack2(float a, float b){
  h2_t h; h.x = (_Float16)a; h.y = (_Float16)b;
  return __builtin_bit_cast(uint, h);
}
__device__ __forceinline__ float f16f(ushortt s){
  return (float)__builtin_bit_cast(_Float16, s);
}
__device__ __forceinline__ ushortt ff16(float f){
  return __builtin_bit_cast(ushortt, (_Float16)f);
}
__device__ __forceinline__ float dot2(uint w, uint h, float acc){
  return __builtin_amdgcn_fdot2(__builtin_bit_cast(h2_t, w),
                                __builtin_bit_cast(h2_t, h), acc, false);
}
__device__ __forceinline__ float d16(uint4 w, uint4 h, float a){
  a = dot2(w.x,h.x,a); a = dot2(w.y,h.y,a);
  a = dot2(w.z,h.z,a); a = dot2(w.w,h.w,a);
  return a;
}
template<int CTRL>
__device__ __forceinline__ float dpp_addf(float x){
  int p = __builtin_amdgcn_update_dpp(0, __float_as_int(x), CTRL, 0xF, 0xF, true);
  return x + __int_as_float(p);
}
template<int CTRL>
__device__ __forceinline__ float dpp_movf(float x){
  return __int_as_float(__builtin_amdgcn_update_dpp(0, __float_as_int(x), CTRL, 0xF, 0xF, true));
}
// sum over 4-lane quads, result in all 4 lanes (verified r4: gx path passed)
__device__ __forceinline__ float red4(float x){
  x = dpp_addf<0xB1>(x); x = dpp_addf<0x4E>(x);
  return x;
}
// sum over 8-lane groups (q = lane&7), result in all 8 lanes (verified r1/r2)
__device__ __forceinline__ float red8(float x){
  x = dpp_addf<0xB1>(x); x = dpp_addf<0x4E>(x);
  int y = __builtin_amdgcn_ds_swizzle(__float_as_int(x), 0x101F);
  return x + __int_as_float(y);
}
__device__ __forceinline__ float sigf(float x){ return 1.0f/(1.0f+__expf(-x)); }
__device__ __forceinline__ float tanhf_(float x){
  x = fminf(15.0f, fmaxf(-15.0f, x));
  float e = __expf(2.0f*x);
  return (e-1.0f)/(e+1.0f);
}

// =================== prep: pack fp32 weights -> f16 images ===================
// PH (REC, 1024 thr, q=tid&7 32-col slice, u=tid>>3 units {2u,2u+1}):
//   uint4 PH[c*1024+tid], c=r*4+k4, r=g*2+s: row=g*256+2u+s, dword e = cols 32q+8k4+2e,+1.
// PI0 (GEMM0): PI0[(r*32+ci)*256 + j] = cols 2ci,2ci+1 of row r*256+j (K=64).
// PI1 (GEMM1, kq=tid&3, j=tid>>2): PI1[(r*32+ci)*1024 + tid] = cols 64kq+2ci,+1 of row r*256+j.
__global__ void prep_kernel(const float* __restrict__ W_ih0, const float* __restrict__ W_hh0,
                            const float* __restrict__ W_ih1, const float* __restrict__ W_hh1,
                            uint* __restrict__ PH0, uint* __restrict__ PH1,
                            uint* __restrict__ PI0, uint* __restrict__ PI1)
{
  int i = blockIdx.x*256 + threadIdx.x;
  if (i < 196608) {
    const float* W = (i < 98304) ? W_hh0 : W_hh1;
    uint* dst = (i < 98304) ? PH0 : PH1;
    int j = i % 98304;
    int e = j&3, r2 = j>>2;
    int tid = r2 & 1023, c = r2 >> 10;
    int q = tid&7, u = tid>>3, k4 = c&3, r = c>>2;
    int g = r>>1, s = r&1;
    int row = g*256 + 2*u + s, col = 32*q + 8*k4 + 2*e;
    dst[j] = pack2(W[row*256+col], W[row*256+col+1]);
  } else if (i < 221184) {
    int j2 = i - 196608;                       // [0, 24576)
    int jj = j2 & 255, rc = j2 >> 8;
    int ci = rc & 31, r = rc >> 5;
    PI0[j2] = pack2(W_ih0[(r*256+jj)*64 + 2*ci], W_ih0[(r*256+jj)*64 + 2*ci + 1]);
  } else if (i < 319488) {
    int j3 = i - 221184;                       // [0, 98304)
    int tid = j3 & 1023, rc = j3 >> 10;
    int ci = rc & 31, r = rc >> 5;
    int kq = tid & 3, jj = tid >> 2;
    int col = 64*kq + 2*ci;
    PI1[j3] = pack2(W_ih1[(r*256+jj)*256 + col], W_ih1[(r*256+jj)*256 + col + 1]);
  }
}

// =================== GEMM0: gx0 = W_ih0 . x + (b_ih0 [+ b_hh0 for r,z]) ===================
// block = (b, 32-t chunk); 512 thr: j=tid&255, th=tid>>8 (16 t's each). Full K=64 per thread.
__global__ __launch_bounds__(512) void gemm0_kernel(
    const float* __restrict__ x, const uint* __restrict__ PI0,
    const float* __restrict__ b_ih0, const float* __restrict__ b_hh0,
    ushortt* __restrict__ gx)
{
  const int blk = blockIdx.x;
  const int b = blk >> 4, t0 = (blk & 15) * 32;
  const int tid = threadIdx.x;
  const int j = tid & 255, th = tid >> 8;
  __shared__ uint xs[32*32];   // [t'][32 uints = 64 f16 cols]
  {
    float4 v = ((const float4*)x)[((size_t)b*TT + t0 + (tid>>4))*16 + (tid&15)];
    xs[(tid>>4)*32 + (tid&15)*2]     = pack2(v.x, v.y);
    xs[(tid>>4)*32 + (tid&15)*2 + 1] = pack2(v.z, v.w);
  }
  uint w[96];
  #pragma unroll
  for (int rc = 0; rc < 96; ++rc) w[rc] = PI0[rc*256 + j];
  const float br = b_ih0[j] + b_hh0[j];
  const float bz = b_ih0[256+j] + b_hh0[256+j];
  const float bn = b_ih0[512+j];
  __syncthreads();
  ushortt* gout = gx + ((size_t)b*TT + t0 + th*16)*768;
  #pragma unroll 1
  for (int tt = 0; tt < 16; ++tt) {
    const uint* xr = xs + (th*16 + tt)*32;
    float ar=0.f, az=0.f, an=0.f;
    #pragma unroll
    for (int c = 0; c < 32; ++c) {
      uint xv = xr[c];
      ar = dot2(w[c],    xv, ar);
      az = dot2(w[32+c], xv, az);
      an = dot2(w[64+c], xv, an);
    }
    gout[j]     = ff16(ar + br);
    gout[256+j] = ff16(az + bz);
    gout[512+j] = ff16(an + bn);
    gout += 768;
  }
}

// =================== GEMM1: gx1 = W_ih1 . h1 + biases ===================
// block = (b, 16-t chunk); 1024 thr: kq=tid&3 (64-col slice), j=tid>>2. red4 over kq.
__global__ __launch_bounds__(1024) void gemm1_kernel(
    const uint* __restrict__ h1, const uint* __restrict__ PI1,
    const float* __restrict__ b_ih1, const float* __restrict__ b_hh1,
    ushortt* __restrict__ gx)
{
  const int blk = blockIdx.x;
  const int b = blk >> 5, t0 = (blk & 31) * 16;
  const int tid = threadIdx.x;
  const int kq = tid & 3, j = tid >> 2;
  __shared__ uint hsT[16*144];   // [t'][36 uint4], padded: phys uint4 slot = s + (s>>3)
  {
    uint2 v = ((const uint2*)(h1 + ((size_t)b*TT + t0)*128))[tid];
    int f = 2*tid, tp = f>>7, c = f&127, s = c>>2, e = c&3;
    *(uint2*)&hsT[tp*144 + (s + (s>>3))*4 + e] = v;
  }
  uint w[96];
  #pragma unroll
  for (int rc = 0; rc < 96; ++rc) w[rc] = PI1[rc*1024 + tid];
  const float br = b_ih1[j] + b_hh1[j];
  const float bz = b_ih1[256+j] + b_hh1[256+j];
  const float bn = b_ih1[512+j];
  __syncthreads();
  ushortt* gout = gx + ((size_t)b*TT + t0)*768;
  #pragma unroll 1
  for (int tt = 0; tt < 16; ++tt) {
    const uint4* hr = (const uint4*)&hsT[tt*144];
    float ar=0.f, az=0.f, an=0.f;
    #pragma unroll
    for (int i = 0; i < 8; ++i) {
      uint4 hv = hr[9*kq + i];
      ar = dot2(w[4*i],hv.x,ar);    ar = dot2(w[4*i+1],hv.y,ar);
      ar = dot2(w[4*i+2],hv.z,ar);  ar = dot2(w[4*i+3],hv.w,ar);
      az = dot2(w[32+4*i],hv.x,az); az = dot2(w[32+4*i+1],hv.y,az);
      az = dot2(w[32+4*i+2],hv.z,az); az = dot2(w[32+4*i+3],hv.w,az);
      an = dot2(w[64+4*i],hv.x,an); an = dot2(w[64+4*i+1],hv.y,an);
      an = dot2(w[64+4*i+2],hv.z,an); an = dot2(w[64+4*i+3],hv.w,an);
    }
    ar = red4(ar); az = red4(az); an = red4(an);
    if (kq == 0) {
      gout[j]     = ff16(ar + br);
      gout[256+j] = ff16(az + bz);
      gout[512+j] = ff16(an + bn);
    }
    gout += 768;
  }
}

// =================== REC: serial GRU recurrence, W_hh fully register-resident ===================
// 128 blocks (1/batch) x 1024 thr. q=tid&7 (32-col k-slice), u=tid>>3 (units 2u,2u+1).
// 96 weight VGPRs/thread; h (f16) double-buffered in 1 KB LDS; ONE barrier/step;
// gx (f16, biases folded) prefetched 2 steps ahead; gate math on lanes q<2.
template<bool IS_L0>
__global__ __launch_bounds__(1024) void rec_kernel(
    const uint4* __restrict__ PH, const ushortt* __restrict__ GX,
    const float* __restrict__ b_hh,
    uint* __restrict__ h1, float* __restrict__ h2o)
{
  const int b = blockIdx.x, tid = threadIdx.x;
  const int q = tid & 7, u = tid >> 3;
  __shared__ uint hs[2][128];
  if (tid < 128) hs[0][tid] = 0;
  uint4 w[24];
  #pragma unroll
  for (int c = 0; c < 24; ++c) w[c] = PH[c*1024 + tid];
  const int j = 2*u + q;                // unit index (valid for q<2)
  const bool gl = (q < 2);
  const ushortt* gxp = GX + (size_t)b*TT*768;
  const float bhn = gl ? b_hh[512 + j] : 0.f;
  ushortt gr0=0, gz0=0, gn0=0, gr1=0, gz1=0, gn1=0;
  if (gl) {
    gr0 = gxp[j]; gz0 = gxp[256+j]; gn0 = gxp[512+j];
    gr1 = gxp[768+j]; gz1 = gxp[768+256+j]; gn1 = gxp[768+512+j];
  }
  float h_old = 0.f;
  __syncthreads();
  int cur = 0;
  #pragma unroll 1
  for (int t = 0; t < TT; ++t) {
    float a0=0.f,a1=0.f,a2=0.f,a3=0.f,a4=0.f,a5=0.f;
    const uint4* hr = (const uint4*)&hs[cur][0];
    #pragma unroll
    for (int k4 = 0; k4 < 4; ++k4) {
      uint4 hk = hr[4*q + k4];
      a0 = d16(w[0*4+k4], hk, a0);   // r gate, unit 2u
      a1 = d16(w[1*4+k4], hk, a1);   // r gate, unit 2u+1
      a2 = d16(w[2*4+k4], hk, a2);   // z gate, unit 2u
      a3 = d16(w[3*4+k4], hk, a3);
      a4 = d16(w[4*4+k4], hk, a4);   // n gate, unit 2u
      a5 = d16(w[5*4+k4], hk, a5);
    }
    a0=red8(a0); a1=red8(a1); a2=red8(a2);
    a3=red8(a3); a4=red8(a4); a5=red8(a5);
    const bool odd = (q & 1);
    float Sr = odd ? a1 : a0;
    float Sz = odd ? a3 : a2;
    float Sn = odd ? a5 : a4;
    float r = sigf(f16f(gr0) + Sr);
    float z = sigf(f16f(gz0) + Sz);
    float n = tanhf_(f16f(gn0) + r*(Sn + bhn));
    float hn = z*(h_old - n) + n;
    if (gl) h_old = hn;
    // rotate gx prefetch (2 ahead; loads drained at the barrier -> latency hidden)
    gr0 = gr1; gz0 = gz1; gn0 = gn1;
    if (gl && t + 2 < TT) {
      const ushortt* p = gxp + (size_t)(t+2)*768;
      gr1 = p[j]; gz1 = p[256+j]; gn1 = p[512+j];
    }
    // publish h
    float hx = dpp_movf<0xB1>(hn);         // q==0 receives q==1's hn
    uint hv2 = pack2(hn, hx);
    if (q == 0) {
      hs[cur^1][u] = hv2;
      if (IS_L0) h1[((size_t)b*TT + t)*128 + u] = hv2;
    }
    if (!IS_L0 && t == TT-1 && gl) h2o[b*256 + j] = hn;
    __syncthreads();
    cur ^= 1;
  }
}

// =================== MLP head ===================
__global__ __launch_bounds__(128) void mlp_kernel(
    const float* __restrict__ h2, const float* __restrict__ W1,
    const float* __restrict__ b1, const float* __restrict__ W2,
    const float* __restrict__ b2, float* __restrict__ out)
{
  __shared__ float hls[256];
  __shared__ float red[128];
  const int b = blockIdx.x, tid = threadIdx.x;
  if (tid < 64) ((float4*)hls)[tid] = ((const float4*)(h2 + (size_t)b*256))[tid];
  __syncthreads();
  float acc = b1[tid];
  const float4* w4 = (const float4*)(W1 + (size_t)tid*256);
  const float4* h4 = (const float4*)hls;
  #pragma unroll 8
  for (int k = 0; k < 64; ++k) {
    float4 w = w4[k]; float4 h = h4[k];
    acc = fmaf(w.x,h.x,acc); acc = fmaf(w.y,h.y,acc);
    acc = fmaf(w.z,h.z,acc); acc = fmaf(w.w,h.w,acc);
  }
  red[tid] = fmaxf(acc, 0.0f) * W2[tid];
  __syncthreads();
  for (int s = 64; s > 0; s >>= 1) {
    if (tid < s) red[tid] += red[tid + s];
    __syncthreads();
  }
  if (tid == 0) out[b] = red[0] + b2[0];
}

extern "C" void kernel_launch(void* const* d_in, const int* in_sizes, int n_in,
                              void* d_out, int out_size, void* d_ws, size_t ws_size,
                              hipStream_t stream)
{
  const float* x     = (const float*)d_in[0];
  const float* W_ih0 = (const float*)d_in[1];
  const float* W_hh0 = (const float*)d_in[2];
  const float* b_ih0 = (const float*)d_in[3];
  const float* b_hh0 = (const float*)d_in[4];
  const float* W_ih1 = (const float*)d_in[5];
  const float* W_hh1 = (const float*)d_in[6];
  const float* b_ih1 = (const float*)d_in[7];
  const float* b_hh1 = (const float*)d_in[8];
  const float* W1    = (const float*)d_in[9];
  const float* b1    = (const float*)d_in[10];
  const float* W2    = (const float*)d_in[11];
  const float* b2    = (const float*)d_in[12];

  char* ws = (char*)d_ws;
  uint*    PH0 = (uint*)(ws + OFF_PH0);
  uint*    PH1 = (uint*)(ws + OFF_PH1);
  uint*    PI0 = (uint*)(ws + OFF_PI0);
  uint*    PI1 = (uint*)(ws + OFF_PI1);
  float*   H2O = (float*)(ws + OFF_H2O);
  uint*    H1  = (uint*)(ws + OFF_H1);
  ushortt* GX  = (ushortt*)(ws + OFF_GX);

  prep_kernel<<<1248, 256, 0, stream>>>(W_ih0, W_hh0, W_ih1, W_hh1, PH0, PH1, PI0, PI1);
  gemm0_kernel<<<2048, 512, 0, stream>>>(x, PI0, b_ih0, b_hh0, GX);
  rec_kernel<true><<<BB, 1024, 0, stream>>>((const uint4*)PH0, GX, b_hh0, H1, nullptr);
  gemm1_kernel<<<4096, 1024, 0, stream>>>(H1, PI1, b_ih1, b_hh1, GX);
  rec_kernel<false><<<BB, 1024, 0, stream>>>((const uint4*)PH1, GX, b_hh1, nullptr, H2O);
  mlp_kernel<<<BB, 128, 0, stream>>>(H2O, W1, b1, W2, b2, (float*)d_out);
}

// Round 7
// 2201.420 us; speedup vs baseline: 5.5258x; 1.0857x over previous
//
#include <hip/hip_runtime.h>
#include <cstdint>
#include <cstddef>

typedef _Float16 h2_t __attribute__((ext_vector_type(2)));
typedef unsigned int uint;
typedef unsigned short ushortt;

#define BB 128
#define TT 512

// ---- ws layout (bytes) ----
#define OFF_PH0 0u            // 24*1024*16 = 393216
#define OFF_PH1 393216u       // 393216
#define OFF_PI0 786432u       // 24576*4 = 98304
#define OFF_PI1 884736u       // 98304*4 = 393216
#define OFF_H2O 1277952u      // 128*256*4 = 131072
#define OFF_H1  1409024u      // 128*512*128*4 = 33554432
#define OFF_GX  34963456u     // 128*512*768*2 = 100663296  (end ~135.6 MB)

__device__ __forceinline__ uint pack2(float a, float b){
  h2_t h; h.x = (_Float16)a; h.y = (_Float16)b;
  return __builtin_bit_cast(uint, h);
}
__device__ __forceinline__ float f16f(ushortt s){
  return (float)__builtin_bit_cast(_Float16, s);
}
__device__ __forceinline__ ushortt ff16(float f){
  return __builtin_bit_cast(ushortt, (_Float16)f);
}
__device__ __forceinline__ float dot2(uint w, uint h, float acc){
  return __builtin_amdgcn_fdot2(__builtin_bit_cast(h2_t, w),
                                __builtin_bit_cast(h2_t, h), acc, false);
}
__device__ __forceinline__ float d16(uint4 w, uint4 h, float a){
  a = dot2(w.x,h.x,a); a = dot2(w.y,h.y,a);
  a = dot2(w.z,h.z,a); a = dot2(w.w,h.w,a);
  return a;
}
template<int CTRL>
__device__ __forceinline__ float dpp_addf(float x){
  int p = __builtin_amdgcn_update_dpp(0, __float_as_int(x), CTRL, 0xF, 0xF, true);
  return x + __int_as_float(p);
}
template<int CTRL>
__device__ __forceinline__ float dpp_movf(float x){
  return __int_as_float(__builtin_amdgcn_update_dpp(0, __float_as_int(x), CTRL, 0xF, 0xF, true));
}
// sum over 4-lane quads, result in all 4 lanes (verified r4/r5)
__device__ __forceinline__ float red4(float x){
  x = dpp_addf<0xB1>(x); x = dpp_addf<0x4E>(x);
  return x;
}
// sum over 8-lane groups (q = lane&7), result in all 8 lanes (verified r1..r5)
__device__ __forceinline__ float red8(float x){
  x = dpp_addf<0xB1>(x); x = dpp_addf<0x4E>(x);
  int y = __builtin_amdgcn_ds_swizzle(__float_as_int(x), 0x101F);
  return x + __int_as_float(y);
}
__device__ __forceinline__ float sigf(float x){ return 1.0f/(1.0f+__expf(-x)); }
__device__ __forceinline__ float tanhf_(float x){
  x = fminf(15.0f, fmaxf(-15.0f, x));
  float e = __expf(2.0f*x);
  return (e-1.0f)/(e+1.0f);
}

// =================== prep: pack fp32 weights -> f16 images (unchanged from r5) ===================
__global__ void prep_kernel(const float* __restrict__ W_ih0, const float* __restrict__ W_hh0,
                            const float* __restrict__ W_ih1, const float* __restrict__ W_hh1,
                            uint* __restrict__ PH0, uint* __restrict__ PH1,
                            uint* __restrict__ PI0, uint* __restrict__ PI1)
{
  int i = blockIdx.x*256 + threadIdx.x;
  if (i < 196608) {
    const float* W = (i < 98304) ? W_hh0 : W_hh1;
    uint* dst = (i < 98304) ? PH0 : PH1;
    int j = i % 98304;
    int e = j&3, r2 = j>>2;
    int tid = r2 & 1023, c = r2 >> 10;
    int q = tid&7, u = tid>>3, k4 = c&3, r = c>>2;
    int g = r>>1, s = r&1;
    int row = g*256 + 2*u + s, col = 32*q + 8*k4 + 2*e;
    dst[j] = pack2(W[row*256+col], W[row*256+col+1]);
  } else if (i < 221184) {
    int j2 = i - 196608;
    int jj = j2 & 255, rc = j2 >> 8;
    int ci = rc & 31, r = rc >> 5;
    PI0[j2] = pack2(W_ih0[(r*256+jj)*64 + 2*ci], W_ih0[(r*256+jj)*64 + 2*ci + 1]);
  } else if (i < 319488) {
    int j3 = i - 221184;
    int tid = j3 & 1023, rc = j3 >> 10;
    int ci = rc & 31, r = rc >> 5;
    int kq = tid & 3, jj = tid >> 2;
    int col = 64*kq + 2*ci;
    PI1[j3] = pack2(W_ih1[(r*256+jj)*256 + col], W_ih1[(r*256+jj)*256 + col + 1]);
  }
}

// =================== GEMM0: gx0 = W_ih0 . x + biases (unchanged) ===================
__global__ __launch_bounds__(512) void gemm0_kernel(
    const float* __restrict__ x, const uint* __restrict__ PI0,
    const float* __restrict__ b_ih0, const float* __restrict__ b_hh0,
    ushortt* __restrict__ gx)
{
  const int blk = blockIdx.x;
  const int b = blk >> 4, t0 = (blk & 15) * 32;
  const int tid = threadIdx.x;
  const int j = tid & 255, th = tid >> 8;
  __shared__ uint xs[32*32];
  {
    float4 v = ((const float4*)x)[((size_t)b*TT + t0 + (tid>>4))*16 + (tid&15)];
    xs[(tid>>4)*32 + (tid&15)*2]     = pack2(v.x, v.y);
    xs[(tid>>4)*32 + (tid&15)*2 + 1] = pack2(v.z, v.w);
  }
  uint w[96];
  #pragma unroll
  for (int rc = 0; rc < 96; ++rc) w[rc] = PI0[rc*256 + j];
  const float br = b_ih0[j] + b_hh0[j];
  const float bz = b_ih0[256+j] + b_hh0[256+j];
  const float bn = b_ih0[512+j];
  __syncthreads();
  ushortt* gout = gx + ((size_t)b*TT + t0 + th*16)*768;
  #pragma unroll 1
  for (int tt = 0; tt < 16; ++tt) {
    const uint* xr = xs + (th*16 + tt)*32;
    float ar=0.f, az=0.f, an=0.f;
    #pragma unroll
    for (int c = 0; c < 32; ++c) {
      uint xv = xr[c];
      ar = dot2(w[c],    xv, ar);
      az = dot2(w[32+c], xv, az);
      an = dot2(w[64+c], xv, an);
    }
    gout[j]     = ff16(ar + br);
    gout[256+j] = ff16(az + bz);
    gout[512+j] = ff16(an + bn);
    gout += 768;
  }
}

// =================== GEMM1: gx1 = W_ih1 . h1 + biases (unchanged) ===================
__global__ __launch_bounds__(1024) void gemm1_kernel(
    const uint* __restrict__ h1, const uint* __restrict__ PI1,
    const float* __restrict__ b_ih1, const float* __restrict__ b_hh1,
    ushortt* __restrict__ gx)
{
  const int blk = blockIdx.x;
  const int b = blk >> 5, t0 = (blk & 31) * 16;
  const int tid = threadIdx.x;
  const int kq = tid & 3, j = tid >> 2;
  __shared__ uint hsT[16*144];
  {
    uint2 v = ((const uint2*)(h1 + ((size_t)b*TT + t0)*128))[tid];
    int f = 2*tid, tp = f>>7, c = f&127, s = c>>2, e = c&3;
    *(uint2*)&hsT[tp*144 + (s + (s>>3))*4 + e] = v;
  }
  uint w[96];
  #pragma unroll
  for (int rc = 0; rc < 96; ++rc) w[rc] = PI1[rc*1024 + tid];
  const float br = b_ih1[j] + b_hh1[j];
  const float bz = b_ih1[256+j] + b_hh1[256+j];
  const float bn = b_ih1[512+j];
  __syncthreads();
  ushortt* gout = gx + ((size_t)b*TT + t0)*768;
  #pragma unroll 1
  for (int tt = 0; tt < 16; ++tt) {
    const uint4* hr = (const uint4*)&hsT[tt*144];
    float ar=0.f, az=0.f, an=0.f;
    #pragma unroll
    for (int i = 0; i < 8; ++i) {
      uint4 hv = hr[9*kq + i];
      ar = dot2(w[4*i],hv.x,ar);    ar = dot2(w[4*i+1],hv.y,ar);
      ar = dot2(w[4*i+2],hv.z,ar);  ar = dot2(w[4*i+3],hv.w,ar);
      az = dot2(w[32+4*i],hv.x,az); az = dot2(w[32+4*i+1],hv.y,az);
      az = dot2(w[32+4*i+2],hv.z,az); az = dot2(w[32+4*i+3],hv.w,az);
      an = dot2(w[64+4*i],hv.x,an); an = dot2(w[64+4*i+1],hv.y,an);
      an = dot2(w[64+4*i+2],hv.z,an); an = dot2(w[64+4*i+3],hv.w,an);
    }
    ar = red4(ar); az = red4(az); an = red4(an);
    if (kq == 0) {
      gout[j]     = ff16(ar + br);
      gout[256+j] = ff16(az + bz);
      gout[512+j] = ff16(an + bn);
    }
    gout += 768;
  }
}

// =================== REC: serial GRU recurrence ===================
// 128 blocks x 1024 thr, q=tid&7 (32-col slice), u=tid>>3 (units 2u,2u+1).
// r7 = r6 with the asm pin fixed: weights held as 96 SCALAR uints, each pinned
// with its own "+v" tie (vector-typed "+v" on uint4 is a tied-indirect
// constraint the AMDGPU backend rejects -> r6 compile failure).
//  (a) __launch_bounds__(1024,4): 128-VGPR budget; pinned weights cannot be
//      re-sunk into the loop (r5: VGPR=64, 393KB/CU/step L2-bound re-stream).
//  (b) h LDS layout padded: phys uint = c + 4*(c>>4) -> b128 reads land on
//      disjoint bank-quads (r5: 4-way conflict, 1.7e7 SQ_LDS_BANK_CONFLICT).
template<bool IS_L0>
__global__ __launch_bounds__(1024, 4) void rec_kernel(
    const uint4* __restrict__ PH, const ushortt* __restrict__ GX,
    const float* __restrict__ b_hh,
    uint* __restrict__ h1, float* __restrict__ h2o)
{
  const int b = blockIdx.x, tid = threadIdx.x;
  const int q = tid & 7, u = tid >> 3;
  __shared__ uint hs[2][160];                 // padded: phys = c + 4*(c>>4)
  if (tid < 128) hs[0][tid + 4*(tid>>4)] = 0;
  uint w[96];
  #pragma unroll
  for (int c = 0; c < 24; ++c) {
    uint4 v = PH[c*1024 + tid];
    w[4*c] = v.x; w[4*c+1] = v.y; w[4*c+2] = v.z; w[4*c+3] = v.w;
  }
  #pragma unroll
  for (int c = 0; c < 96; ++c) asm volatile("" : "+v"(w[c]));  // scalar pins: not remat-able
  const int j = 2*u + q;                // unit index (valid for q<2)
  const bool gl = (q < 2);
  const ushortt* gxp = GX + (size_t)b*TT*768;
  const float bhn = gl ? b_hh[512 + j] : 0.f;
  ushortt gr0=0, gz0=0, gn0=0, gr1=0, gz1=0, gn1=0;
  if (gl) {
    gr0 = gxp[j]; gz0 = gxp[256+j]; gn0 = gxp[512+j];
    gr1 = gxp[768+j]; gz1 = gxp[768+256+j]; gn1 = gxp[768+512+j];
  }
  float h_old = 0.f;
  __syncthreads();
  int cur = 0;
  #pragma unroll 1
  for (int t = 0; t < TT; ++t) {
    float a0=0.f,a1=0.f,a2=0.f,a3=0.f,a4=0.f,a5=0.f;
    const uint4* hr = (const uint4*)&hs[cur][0];
    #pragma unroll
    for (int k4 = 0; k4 < 4; ++k4) {
      uint4 hk = hr[5*q + k4];          // phys 20q+4k4: disjoint bank-quads across q
      a0 = dot2(w[(0*4+k4)*4+0], hk.x, a0); a0 = dot2(w[(0*4+k4)*4+1], hk.y, a0);
      a0 = dot2(w[(0*4+k4)*4+2], hk.z, a0); a0 = dot2(w[(0*4+k4)*4+3], hk.w, a0);
      a1 = dot2(w[(1*4+k4)*4+0], hk.x, a1); a1 = dot2(w[(1*4+k4)*4+1], hk.y, a1);
      a1 = dot2(w[(1*4+k4)*4+2], hk.z, a1); a1 = dot2(w[(1*4+k4)*4+3], hk.w, a1);
      a2 = dot2(w[(2*4+k4)*4+0], hk.x, a2); a2 = dot2(w[(2*4+k4)*4+1], hk.y, a2);
      a2 = dot2(w[(2*4+k4)*4+2], hk.z, a2); a2 = dot2(w[(2*4+k4)*4+3], hk.w, a2);
      a3 = dot2(w[(3*4+k4)*4+0], hk.x, a3); a3 = dot2(w[(3*4+k4)*4+1], hk.y, a3);
      a3 = dot2(w[(3*4+k4)*4+2], hk.z, a3); a3 = dot2(w[(3*4+k4)*4+3], hk.w, a3);
      a4 = dot2(w[(4*4+k4)*4+0], hk.x, a4); a4 = dot2(w[(4*4+k4)*4+1], hk.y, a4);
      a4 = dot2(w[(4*4+k4)*4+2], hk.z, a4); a4 = dot2(w[(4*4+k4)*4+3], hk.w, a4);
      a5 = dot2(w[(5*4+k4)*4+0], hk.x, a5); a5 = dot2(w[(5*4+k4)*4+1], hk.y, a5);
      a5 = dot2(w[(5*4+k4)*4+2], hk.z, a5); a5 = dot2(w[(5*4+k4)*4+3], hk.w, a5);
    }
    a0=red8(a0); a1=red8(a1); a2=red8(a2);
    a3=red8(a3); a4=red8(a4); a5=red8(a5);
    const bool odd = (q & 1);
    float Sr = odd ? a1 : a0;
    float Sz = odd ? a3 : a2;
    float Sn = odd ? a5 : a4;
    float r = sigf(f16f(gr0) + Sr);
    float z = sigf(f16f(gz0) + Sz);
    float n = tanhf_(f16f(gn0) + r*(Sn + bhn));
    float hn = z*(h_old - n) + n;
    if (gl) h_old = hn;
    gr0 = gr1; gz0 = gz1; gn0 = gn1;
    if (gl && t + 2 < TT) {
      const ushortt* p = gxp + (size_t)(t+2)*768;
      gr1 = p[j]; gz1 = p[256+j]; gn1 = p[512+j];
    }
    float hx = dpp_movf<0xB1>(hn);
    uint hv2 = pack2(hn, hx);
    if (q == 0) {
      hs[cur^1][u + 4*(u>>4)] = hv2;
      if (IS_L0) h1[((size_t)b*TT + t)*128 + u] = hv2;
    }
    if (!IS_L0 && t == TT-1 && gl) h2o[b*256 + j] = hn;
    __syncthreads();
    cur ^= 1;
  }
}

// =================== MLP head (unchanged) ===================
__global__ __launch_bounds__(128) void mlp_kernel(
    const float* __restrict__ h2, const float* __restrict__ W1,
    const float* __restrict__ b1, const float* __restrict__ W2,
    const float* __restrict__ b2, float* __restrict__ out)
{
  __shared__ float hls[256];
  __shared__ float red[128];
  const int b = blockIdx.x, tid = threadIdx.x;
  if (tid < 64) ((float4*)hls)[tid] = ((const float4*)(h2 + (size_t)b*256))[tid];
  __syncthreads();
  float acc = b1[tid];
  const float4* w4 = (const float4*)(W1 + (size_t)tid*256);
  const float4* h4 = (const float4*)hls;
  #pragma unroll 8
  for (int k = 0; k < 64; ++k) {
    float4 w = w4[k]; float4 h = h4[k];
    acc = fmaf(w.x,h.x,acc); acc = fmaf(w.y,h.y,acc);
    acc = fmaf(w.z,h.z,acc); acc = fmaf(w.w,h.w,acc);
  }
  red[tid] = fmaxf(acc, 0.0f) * W2[tid];
  __syncthreads();
  for (int s = 64; s > 0; s >>= 1) {
    if (tid < s) red[tid] += red[tid + s];
    __syncthreads();
  }
  if (tid == 0) out[b] = red[0] + b2[0];
}

extern "C" void kernel_launch(void* const* d_in, const int* in_sizes, int n_in,
                              void* d_out, int out_size, void* d_ws, size_t ws_size,
                              hipStream_t stream)
{
  const float* x     = (const float*)d_in[0];
  const float* W_ih0 = (const float*)d_in[1];
  const float* W_hh0 = (const float*)d_in[2];
  const float* b_ih0 = (const float*)d_in[3];
  const float* b_hh0 = (const float*)d_in[4];
  const float* W_ih1 = (const float*)d_in[5];
  const float* W_hh1 = (const float*)d_in[6];
  const float* b_ih1 = (const float*)d_in[7];
  const float* b_hh1 = (const float*)d_in[8];
  const float* W1    = (const float*)d_in[9];
  const float* b1    = (const float*)d_in[10];
  const float* W2    = (const float*)d_in[11];
  const float* b2    = (const float*)d_in[12];

  char* ws = (char*)d_ws;
  uint*    PH0 = (uint*)(ws + OFF_PH0);
  uint*    PH1 = (uint*)(ws + OFF_PH1);
  uint*    PI0 = (uint*)(ws + OFF_PI0);
  uint*    PI1 = (uint*)(ws + OFF_PI1);
  float*   H2O = (float*)(ws + OFF_H2O);
  uint*    H1  = (uint*)(ws + OFF_H1);
  ushortt* GX  = (ushortt*)(ws + OFF_GX);

  prep_kernel<<<1248, 256, 0, stream>>>(W_ih0, W_hh0, W_ih1, W_hh1, PH0, PH1, PI0, PI1);
  gemm0_kernel<<<2048, 512, 0, stream>>>(x, PI0, b_ih0, b_hh0, GX);
  rec_kernel<true><<<BB, 1024, 0, stream>>>((const uint4*)PH0, GX, b_hh0, H1, nullptr);
  gemm1_kernel<<<4096, 1024, 0, stream>>>(H1, PI1, b_ih1, b_hh1, GX);
  rec_kernel<false><<<BB, 1024, 0, stream>>>((const uint4*)PH1, GX, b_hh1, nullptr, H2O);
  mlp_kernel<<<BB, 128, 0, stream>>>(H2O, W1, b1, W2, b2, (float*)d_out);
}